// Round 2
// baseline (347.975 us; speedup 1.0000x reference)
//
#include <hip/hip_runtime.h>

#define SEQ    256
#define FEAT   768
#define WIN    3
#define FILT   6
#define KTOT   (WIN * FEAT)        // 2304
#define WELEMS (KTOT * FILT)       // 13824 floats
#define NCHUNK (WELEMS / 24)       // 576 chunks of 24 floats (4 k-rows x 6)
#define CSTR4  7                   // chunk stride in float4 (24 floats + 4 pad)
#define NB     8                   // batches per wave-group
#define BLOCK  1024
#define NWAVES (BLOCK / 64)
#define BATCH  256
#define NGROUPS (BATCH / NB)       // 32

// One block per s. W[s] staged to LDS in padded 28-float chunks so each
// lane's 24-float fragment reads as 6 aligned ds_read_b128 with only 2-way
// bank aliasing (free). x read as float4 (1KB/wave-instr, BW-bound not
// latency-bound). Reduction: halving tree (51 shfl/group vs 288 butterfly).
__global__ __launch_bounds__(BLOCK, 4)
void pos_linear_kernel(const float* __restrict__ x,
                       const float* __restrict__ W,
                       const float* __restrict__ bias,
                       float* __restrict__ out) {
    __shared__ float4 wlds4[NCHUNK * CSTR4];   // 64512 B
    const int s   = blockIdx.x;
    const int tid = threadIdx.x;

    // Stage W[s] -> LDS. Global float4 i covers floats [4i,4i+4); chunk
    // c = i/6 holds floats [24c,24c+24) at LDS float4 offset c*7 + (i%6).
    {
        const float4* src = (const float4*)(W + (size_t)s * WELEMS);
        for (int i = tid; i < WELEMS / 4; i += BLOCK) {
            const int c = i / 6, j = i - c * 6;
            wlds4[c * CSTR4 + j] = src[i];
        }
    }
    __syncthreads();

    const int lane = tid & 63;
    const int wave = tid >> 6;

    for (int g = wave; g < NGROUPS; g += NWAVES) {
        const int b0 = g * NB;

        float acc[NB][FILT];
        #pragma unroll
        for (int nb = 0; nb < NB; ++nb)
            #pragma unroll
            for (int o = 0; o < FILT; ++o) acc[nb][o] = 0.f;

        #pragma unroll
        for (int w = 0; w < WIN; ++w) {
            const int r = s - 1 + w;
            if (r < 0 || r >= SEQ) continue;          // zero-pad (uniform)
            const float* xrow0 = x + ((size_t)b0 * SEQ + r) * FEAT;

            for (int i = 0; i < FEAT / 256; ++i) {    // 3 iters, 64 lanes x f4
                const int f4 = lane + 64 * i;         // float4 index within row

                // W fragment: chunk (w*192 + f4) = k-rows [4f4..4f4+3] x 6
                float4 wv4[6];
                {
                    const float4* wc = wlds4 + (size_t)(w * (FEAT / 4) + f4) * CSTR4;
                    #pragma unroll
                    for (int rr = 0; rr < 6; ++rr) wv4[rr] = wc[rr];
                }
                const float* wv = (const float*)wv4;  // wv[ff*6+o]

                float4 xv[NB];                        // 8x global_load_dwordx4
                #pragma unroll
                for (int nb = 0; nb < NB; ++nb)
                    xv[nb] = *(const float4*)(xrow0 + (size_t)nb * SEQ * FEAT + 4 * f4);

                #pragma unroll
                for (int nb = 0; nb < NB; ++nb) {
                    const float* xf = (const float*)&xv[nb];
                    #pragma unroll
                    for (int ff = 0; ff < 4; ++ff)
                        #pragma unroll
                        for (int o = 0; o < FILT; ++o)
                            acc[nb][o] = fmaf(xf[ff], wv[ff * FILT + o], acc[nb][o]);
                }
            }
        }

        // Halving-tree reduce: 48 values over 64 lanes.
        // Step m (bit b): keep lower half if bit clear, upper if set;
        // send the non-kept half. After steps m=1,2,4,8 each lane holds 3
        // partials; full-reduce those over m=16,32.
        float v[NB * FILT];
        #pragma unroll
        for (int nb = 0; nb < NB; ++nb)
            #pragma unroll
            for (int o = 0; o < FILT; ++o) v[nb * FILT + o] = acc[nb][o];

        #pragma unroll
        for (int step = 0; step < 4; ++step) {
            const int m = 1 << step;
            const int half = 48 >> (step + 1);        // 24,12,6,3
            const bool upper = (lane & m) != 0;
            #pragma unroll
            for (int j = 0; j < half; ++j) {
                float snd = upper ? v[j] : v[j + half];
                float kep = upper ? v[j + half] : v[j];
                v[j] = kep + __shfl_xor(snd, m, 64);
            }
        }
        #pragma unroll
        for (int j = 0; j < 3; ++j) {
            v[j] += __shfl_xor(v[j], 16, 64);
            v[j] += __shfl_xor(v[j], 32, 64);
        }

        // lane<16: holds sums idx = 3*bitrev4(lane) + j  (j=0..2).
        // idx -> (nb = idx/6, o = idx%6).
        if (lane < 16) {
            const int gidx = ((lane & 1) << 3) | ((lane & 2) << 1) |
                             ((lane & 4) >> 1) | ((lane & 8) >> 3);
            #pragma unroll
            for (int j = 0; j < 3; ++j) {
                const int idx = 3 * gidx + j;
                const int nb  = idx / FILT;
                const int o   = idx - nb * FILT;
                float r0 = v[j] + bias[s * FILT + o];
                r0 = r0 > 0.f ? r0 : 0.f;
                out[((size_t)(b0 + nb) * SEQ + s) * FILT + o] = r0;
            }
        }
    }
}

extern "C" void kernel_launch(void* const* d_in, const int* in_sizes, int n_in,
                              void* d_out, int out_size, void* d_ws, size_t ws_size,
                              hipStream_t stream) {
    const float* x   = (const float*)d_in[0];  // (256, 256, 768) fp32
    const float* W   = (const float*)d_in[1];  // (256, 2304, 6) fp32
    const float* b   = (const float*)d_in[2];  // (256, 6) fp32
    float*       out = (float*)d_out;          // (256, 256, 6) fp32
    (void)in_sizes; (void)n_in; (void)out_size; (void)d_ws; (void)ws_size;
    pos_linear_kernel<<<SEQ, BLOCK, 0, stream>>>(x, W, b, out);
}